// Round 5
// baseline (503.406 us; speedup 1.0000x reference)
//
#include <hip/hip_runtime.h>
#include <hip/hip_bf16.h>
#include <cstdint>
#include <cstddef>

#define D_IN  512
#define D_H   128
#define D_OUT 64
#define SB    64    // stats partial slots (atomic spread)

typedef __attribute__((ext_vector_type(8))) short bf16x8;
typedef __attribute__((ext_vector_type(4))) float f32x4;

__device__ __forceinline__ float bf2f(unsigned short u) {
  union { unsigned int i; float f; } v; v.i = ((unsigned int)u) << 16; return v.f;
}
__device__ __forceinline__ unsigned short f2bf(float f) {
  union { unsigned int i; float f; } v; v.f = f;
  unsigned int r = v.i + 0x7FFFu + ((v.i >> 16) & 1u);
  return (unsigned short)(r >> 16);
}
__device__ __forceinline__ unsigned int pk_bf16(float a, float b) {
  union { __hip_bfloat162 h; unsigned int u; } cv;
  cv.h = __float22bfloat162_rn(make_float2(a, b));
  return cv.u;
}

// accumulate one packed-bf16 pair with weight W into a0 (low), a1 (high)
#define ACC2(P, W) { unsigned int _p = (P); \
    union { unsigned int i; float f; } _lo, _hi; \
    _lo.i = _p << 16; _hi.i = _p & 0xFFFF0000u; \
    a0 += (W) * _lo.f; a1 += (W) * _hi.f; }

// ---------------- workspace layout (bytes); ws_size ~800MB -------------------
#define OFF_RP    0u          // row_ptr int32[100001]
#define OFF_W0T   400384u     // W0^T bf16 128x512
#define OFF_PSUM  548096u     // fp32[SB][128] (32KB used)
#define OFF_PSQ   679168u     // fp32[SB][128] (32KB used)
#define OFF_H     810240u     // h bf16-packed 100000x128
#define END_H     26410240u   // + hw bf16 100000x64
#define OFF_XW    39210240u   // xw bf16-packed 100000x128
#define END_XW    64810240u

// ---- k_init: W0 transpose only (256 blocks) --------------------------------
__global__ void k_init(const float* __restrict__ W0, unsigned short* __restrict__ W0t) {
  int idx = blockIdx.x * 256 + threadIdx.x;    // 65536 total
  int k = idx & (D_IN - 1);
  int nn = idx >> 9;
  W0t[nn * D_IN + k] = f2bf(W0[k * D_H + nn]);
}

// ---- GEMM1: xw(bf16) = x(fp32) @ W0. tile 128x128, BK=32, dbuf LDS.
// Extra blocks [GB,GB+RB): rp binsearch; [GB+RB]: zero psum/psq.
__global__ __launch_bounds__(256) void k_gemm1(const float* __restrict__ A,
                                               const unsigned short* __restrict__ Bt,
                                               unsigned short* __restrict__ C,
                                               const int* __restrict__ row,
                                               int* __restrict__ rp,
                                               float* __restrict__ psum,
                                               float* __restrict__ psq,
                                               int M, int E, int GB, int RB) {
  int b = blockIdx.x;
  if (b >= GB) {
    int bb = b - GB;
    if (bb < RB) {
      int i = bb * 256 + threadIdx.x;
      if (i <= M) {
        int lo = 0, hi = E;
        while (lo < hi) { int mid = (lo + hi) >> 1; if (row[mid] < i) lo = mid + 1; else hi = mid; }
        rp[i] = lo;
      }
    } else {
      for (int i = threadIdx.x; i < SB * 128; i += 256) { psum[i] = 0.f; psq[i] = 0.f; }
    }
    return;
  }
  __shared__ unsigned short Ash[2][4096];
  __shared__ unsigned short Bsh[2][4096];
  const int tid = threadIdx.x, lane = tid & 63, wave = tid >> 6;
  const int wm = (wave >> 1) * 64, wn = (wave & 1) * 64;
  const int m0 = b * 128, quad = lane >> 4, l16 = lane & 15;
  f32x4 acc[4][4] = {};
  int am[2], ak[2];
  const float* aptr[2];
  const unsigned short* bptr[2];
#pragma unroll
  for (int i = 0; i < 2; ++i) {
    int c = tid + i * 256;
    am[i] = c >> 2; ak[i] = c & 3;
    int gm = m0 + am[i]; if (gm >= M) gm = M - 1;
    aptr[i] = A + (size_t)gm * D_IN + ak[i] * 8;
    bptr[i] = Bt + (size_t)am[i] * D_IN + ak[i] * 8;
  }
  f32x4 areg[2][2]; bf16x8 breg[2];
#pragma unroll
  for (int i = 0; i < 2; ++i) {
    areg[i][0] = *(const f32x4*)(aptr[i]);
    areg[i][1] = *(const f32x4*)(aptr[i] + 4);
    breg[i]    = *(const bf16x8*)(bptr[i]);
  }
  const int NIT = D_IN / 32;
  for (int it = 0; it < NIT; ++it) {
    const int buf = it & 1;
    unsigned short* ash = Ash[buf];
    unsigned short* bsh = Bsh[buf];
#pragma unroll
    for (int i = 0; i < 2; ++i) {
      unsigned int pk4[4];
      pk4[0] = pk_bf16(areg[i][0][0], areg[i][0][1]);
      pk4[1] = pk_bf16(areg[i][0][2], areg[i][0][3]);
      pk4[2] = pk_bf16(areg[i][1][0], areg[i][1][1]);
      pk4[3] = pk_bf16(areg[i][1][2], areg[i][1][3]);
      *(uint4*)&ash[(ak[i] * 128 + am[i]) * 8] = *(uint4*)pk4;
      *(bf16x8*)&bsh[(ak[i] * 128 + am[i]) * 8] = breg[i];
    }
    __syncthreads();
    if (it + 1 < NIT) {
      int k0 = (it + 1) * 32;
#pragma unroll
      for (int i = 0; i < 2; ++i) {
        areg[i][0] = *(const f32x4*)(aptr[i] + k0);
        areg[i][1] = *(const f32x4*)(aptr[i] + k0 + 4);
        breg[i]    = *(const bf16x8*)(bptr[i] + k0);
      }
    }
    bf16x8 af[4], bfv[4];
#pragma unroll
    for (int mf = 0; mf < 4; ++mf)
      af[mf] = *(const bf16x8*)&ash[(quad * 128 + (wm + mf * 16 + l16)) * 8];
#pragma unroll
    for (int nf = 0; nf < 4; ++nf)
      bfv[nf] = *(const bf16x8*)&bsh[(quad * 128 + (wn + nf * 16 + l16)) * 8];
#pragma unroll
    for (int mf = 0; mf < 4; ++mf)
#pragma unroll
      for (int nf = 0; nf < 4; ++nf)
        acc[mf][nf] = __builtin_amdgcn_mfma_f32_16x16x32_bf16(af[mf], bfv[nf], acc[mf][nf], 0, 0, 0);
  }
  // C/D layout: row = quad*4 + i, col = lane&15 [m89/m91-verified]
#pragma unroll
  for (int mf = 0; mf < 4; ++mf)
#pragma unroll
    for (int nf = 0; nf < 4; ++nf)
#pragma unroll
      for (int i = 0; i < 4; ++i) {
        int r = m0 + wm + mf * 16 + quad * 4 + i;
        int cc = wn + nf * 16 + l16;
        if (r < M) C[(size_t)r * D_H + cc] = f2bf(acc[mf][nf][i]);
      }
}

// ---- SpMM1 multi-pass (4 x 32 features): h = relu(adj @ xw + b0) + stats.
// 16 lanes own one node (lane = 1 uint = 2 features); per edge per pass the
// group reads exactly one 64B line. Pass working set 6.4MB -> per-XCD L2-hot.
__global__ __launch_bounds__(256) void k_spmm1(const unsigned int* __restrict__ xw2,
                                               const float* __restrict__ adj,
                                               const int* __restrict__ col,
                                               const int* __restrict__ rp,
                                               const float* __restrict__ b0,
                                               unsigned int* __restrict__ h2,
                                               float* __restrict__ psum,
                                               float* __restrict__ psq,
                                               int n, int PB) {
  __shared__ float sE[4][16], sO[4][16], qE[4][16], qO[4][16];
  const int t = threadIdx.x, wave = t >> 6, l = t & 63;
  const int g = l >> 4, l16 = l & 15;
  const int pass = blockIdx.x / PB;
  const int nb = blockIdx.x - pass * PB;
  const int node = nb * 16 + wave * 4 + g;
  const unsigned int* src = xw2 + pass * 16 + l16;
  float r0 = 0.f, r1 = 0.f;
  if (node < n) {
    const int e0 = rp[node], e1 = rp[node + 1];
    float a0 = 0.f, a1 = 0.f;
    for (int e = e0; e < e1; e += 4) {
      int i1 = e + 1 < e1 ? e + 1 : e;
      int i2 = e + 2 < e1 ? e + 2 : e;
      int i3 = e + 3 < e1 ? e + 3 : e;
      int   c0 = col[e],  c1 = col[i1], c2 = col[i2], c3 = col[i3];
      float w0 = adj[e];
      float w1 = e + 1 < e1 ? adj[i1] : 0.f;
      float w2 = e + 2 < e1 ? adj[i2] : 0.f;
      float w3 = e + 3 < e1 ? adj[i3] : 0.f;
      unsigned int p0 = src[(size_t)c0 * 64];
      unsigned int p1 = src[(size_t)c1 * 64];
      unsigned int p2 = src[(size_t)c2 * 64];
      unsigned int p3 = src[(size_t)c3 * 64];
      ACC2(p0, w0); ACC2(p1, w1); ACC2(p2, w2); ACC2(p3, w3);
    }
    float2 bb = *(const float2*)(b0 + pass * 32 + 2 * l16);
    r0 = fmaxf(a0 + bb.x, 0.f);
    r1 = fmaxf(a1 + bb.y, 0.f);
    h2[(size_t)node * 64 + pass * 16 + l16] =
        ((unsigned int)f2bf(r1) << 16) | (unsigned int)f2bf(r0);
  }
  // stats: combine 4 node-groups (lanes l16, l16+16, +32, +48), then 4 waves
  float s0 = r0, s1 = r1, q0 = r0 * r0, q1 = r1 * r1;
  s0 += __shfl_xor(s0, 16, 64); s0 += __shfl_xor(s0, 32, 64);
  s1 += __shfl_xor(s1, 16, 64); s1 += __shfl_xor(s1, 32, 64);
  q0 += __shfl_xor(q0, 16, 64); q0 += __shfl_xor(q0, 32, 64);
  q1 += __shfl_xor(q1, 16, 64); q1 += __shfl_xor(q1, 32, 64);
  if (g == 0) { sE[wave][l16] = s0; sO[wave][l16] = s1;
                qE[wave][l16] = q0; qO[wave][l16] = q1; }
  __syncthreads();
  if (t < 16) {
    float S0 = sE[0][t] + sE[1][t] + sE[2][t] + sE[3][t];
    float S1 = sO[0][t] + sO[1][t] + sO[2][t] + sO[3][t];
    float Q0 = qE[0][t] + qE[1][t] + qE[2][t] + qE[3][t];
    float Q1 = qO[0][t] + qO[1][t] + qO[2][t] + qO[3][t];
    int base = (blockIdx.x & (SB - 1)) * 128 + pass * 32 + 2 * t;
    atomicAdd(&psum[base],     S0);
    atomicAdd(&psum[base + 1], S1);
    atomicAdd(&psq[base],      Q0);
    atomicAdd(&psq[base + 1],  Q1);
  }
}

// ---- GEMM2 (+inline BN prep): hw(bf16) = h(bf16) @ (istd*W1) + cvec.
// Each block redundantly reduces psum/psq (SB=64 slots, L2-hot) -> mean/istd,
// builds W1'^T in LDS, computes cvec in LDS. Deterministic across blocks.
__global__ __launch_bounds__(256) void k_gemm2(const unsigned short* __restrict__ A,
                                               const float* __restrict__ psum,
                                               const float* __restrict__ psq,
                                               const float* __restrict__ W1,
                                               unsigned short* __restrict__ Cout,
                                               int M, int n) {
  __shared__ float rs[256], rq[256];
  __shared__ float mean_s[128], istd_s[128];
  __shared__ float cvec_s[64];
  __shared__ unsigned short BF[1024 * 8];   // [kk8 0..15][nn 0..63][8] = 16KB
  __shared__ unsigned short Ash[4096];
  const int tid = threadIdx.x, lane = tid & 63, wave = tid >> 6;
  // --- prep ---
  {
    int f = tid & 127, hh = tid >> 7;
    float s = 0.f, q = 0.f;
#pragma unroll 8
    for (int bsl = hh * (SB / 2); bsl < (hh + 1) * (SB / 2); ++bsl) {
      s += psum[bsl * 128 + f]; q += psq[bsl * 128 + f];
    }
    rs[tid] = s; rq[tid] = q;
  }
  __syncthreads();
  if (tid < 128) {
    float s = rs[tid] + rs[tid + 128];
    float q = rq[tid] + rq[tid + 128];
    float m = s / (float)n;
    float var = q / (float)n - m * m;
    if (var < 0.f) var = 0.f;
    mean_s[tid] = m;
    istd_s[tid] = rsqrtf(var + 1e-5f);
  }
  __syncthreads();
  for (int idx = tid; idx < 1024; idx += 256) {   // BF[kk8][nn][j]
    int kk8 = idx >> 6, nn = idx & 63;
    unsigned short* dst = &BF[idx * 8];
#pragma unroll
    for (int j = 0; j < 8; ++j) {
      int k = kk8 * 8 + j;
      dst[j] = f2bf(istd_s[k] * W1[k * D_OUT + nn]);
    }
  }
  {  // cvec partials (reuse rs)
    int o = tid & 63, part = tid >> 6;
    float a = 0.f;
    for (int k = part * 32; k < part * 32 + 32; ++k)
      a += mean_s[k] * istd_s[k] * W1[k * D_OUT + o];
    rs[tid] = a;
  }
  __syncthreads();
  if (tid < D_OUT)
    cvec_s[tid] = -(rs[tid] + rs[tid + 64] + rs[tid + 128] + rs[tid + 192]);
  // --- GEMM ---
  const int wm = wave * 32, m0 = blockIdx.x * 128;
  const int quad = lane >> 4, l16 = lane & 15;
  f32x4 acc[2][4] = {};
  for (int k0 = 0; k0 < D_H; k0 += 32) {
    __syncthreads();
#pragma unroll
    for (int i = 0; i < 2; ++i) {
      int c = tid + i * 256;
      int m = c >> 2, k8 = c & 3;
      int gm = m0 + m; if (gm >= M) gm = M - 1;
      *(bf16x8*)&Ash[(k8 * 128 + m) * 8] = *(const bf16x8*)&A[(size_t)gm * D_H + k0 + k8 * 8];
    }
    __syncthreads();
    bf16x8 af[2], bfv[4];
#pragma unroll
    for (int mf = 0; mf < 2; ++mf)
      af[mf] = *(const bf16x8*)&Ash[(quad * 128 + (wm + mf * 16 + l16)) * 8];
#pragma unroll
    for (int nf = 0; nf < 4; ++nf)
      bfv[nf] = *(const bf16x8*)&BF[(((k0 >> 3) + quad) * 64 + nf * 16 + l16) * 8];
#pragma unroll
    for (int mf = 0; mf < 2; ++mf)
#pragma unroll
      for (int nf = 0; nf < 4; ++nf)
        acc[mf][nf] = __builtin_amdgcn_mfma_f32_16x16x32_bf16(af[mf], bfv[nf], acc[mf][nf], 0, 0, 0);
  }
#pragma unroll
  for (int mf = 0; mf < 2; ++mf)
#pragma unroll
    for (int nf = 0; nf < 4; ++nf)
#pragma unroll
      for (int i = 0; i < 4; ++i) {
        int r = m0 + wm + mf * 16 + quad * 4 + i;
        int cc = nf * 16 + l16;
        if (r < M) Cout[(size_t)r * 64 + cc] = f2bf(acc[mf][nf][i] + cvec_s[cc]);
      }
}

// ---- SpMM2 multi-pass (2 x 32 features): out(fp32) = adj @ hw + b1.
// 16 lanes own one node; per edge per pass one 64B line; no reduce.
__global__ __launch_bounds__(256) void k_spmm2(const unsigned int* __restrict__ hw2,
                                               const float* __restrict__ adj,
                                               const int* __restrict__ col,
                                               const int* __restrict__ rp,
                                               const float* __restrict__ b1,
                                               float* __restrict__ outp,
                                               int n, int PB) {
  const int t = threadIdx.x, wave = t >> 6, l = t & 63;
  const int g = l >> 4, l16 = l & 15;
  const int pass = blockIdx.x / PB;
  const int nb = blockIdx.x - pass * PB;
  const int node = nb * 16 + wave * 4 + g;
  if (node >= n) return;
  const unsigned int* src = hw2 + pass * 16 + l16;
  const int e0 = rp[node], e1 = rp[node + 1];
  float a0 = 0.f, a1 = 0.f;
  for (int e = e0; e < e1; e += 4) {
    int i1 = e + 1 < e1 ? e + 1 : e;
    int i2 = e + 2 < e1 ? e + 2 : e;
    int i3 = e + 3 < e1 ? e + 3 : e;
    int   c0 = col[e],  c1 = col[i1], c2 = col[i2], c3 = col[i3];
    float w0 = adj[e];
    float w1 = e + 1 < e1 ? adj[i1] : 0.f;
    float w2 = e + 2 < e1 ? adj[i2] : 0.f;
    float w3 = e + 3 < e1 ? adj[i3] : 0.f;
    unsigned int p0 = src[(size_t)c0 * 32];
    unsigned int p1 = src[(size_t)c1 * 32];
    unsigned int p2 = src[(size_t)c2 * 32];
    unsigned int p3 = src[(size_t)c3 * 32];
    ACC2(p0, w0); ACC2(p1, w1); ACC2(p2, w2); ACC2(p3, w3);
  }
  float2 bb = *(const float2*)(b1 + pass * 32 + 2 * l16);
  float2 r; r.x = a0 + bb.x; r.y = a1 + bb.y;
  *(float2*)(outp + (size_t)node * 64 + pass * 32 + 2 * l16) = r;
}

extern "C" void kernel_launch(void* const* d_in, const int* in_sizes, int n_in,
                              void* d_out, int out_size, void* d_ws, size_t ws_size,
                              hipStream_t stream) {
  const float* x   = (const float*)d_in[0];
  const float* W0  = (const float*)d_in[1];
  const float* b0  = (const float*)d_in[2];
  const float* W1  = (const float*)d_in[3];
  const float* b1  = (const float*)d_in[4];
  const float* adj = (const float*)d_in[5];
  const int* row = (const int*)d_in[6];
  const int* col = (const int*)d_in[7];
  const int N = in_sizes[0] / D_IN;
  const int E = in_sizes[5];

  char* ws = (char*)d_ws;
  int*            rp   = (int*)(ws + OFF_RP);
  unsigned short* W0t  = (unsigned short*)(ws + OFF_W0T);
  float*          psum = (float*)(ws + OFF_PSUM);
  float*          psq  = (float*)(ws + OFF_PSQ);
  unsigned short* h    = (unsigned short*)(ws + OFF_H);

  const bool big_ws = (ws_size >= (size_t)END_XW);
  unsigned short* xw   = big_ws ? (unsigned short*)(ws + OFF_XW) : (unsigned short*)d_out;
  unsigned short* hwp  = big_ws ? (unsigned short*)(ws + END_H)  : (unsigned short*)d_out;
  float*          outd = (float*)d_out;

  const int GB = (N + 127) / 128;
  const int RB = (N + 1 + 255) / 256;
  const int PB = (N + 15) / 16;
  k_init<<<(D_IN * D_H) / 256, 256, 0, stream>>>(W0, W0t);
  k_gemm1<<<GB + RB + 1, 256, 0, stream>>>(x, W0t, xw, row, rp, psum, psq, N, E, GB, RB);
  k_spmm1<<<4 * PB, 256, 0, stream>>>((const unsigned int*)xw, adj, col, rp, b0,
                                      (unsigned int*)h, psum, psq, N, PB);
  k_gemm2<<<GB, 256, 0, stream>>>(h, psum, psq, W1, hwp, N, N);
  k_spmm2<<<2 * PB, 256, 0, stream>>>((const unsigned int*)hwp, adj, col, rp, b1,
                                      outd, N, PB);
}